// Round 7
// baseline (292.909 us; speedup 1.0000x reference)
//
#include <hip/hip_runtime.h>
#include <hip/hip_bf16.h>
#include <float.h>

#define B_   4
#define N_   2048
#define DIM_ 512
#define H_   8
#define DH_  64

typedef unsigned short ushort;
typedef __attribute__((ext_vector_type(8))) short short8;
typedef __attribute__((ext_vector_type(4))) float f32x4;

__device__ __forceinline__ ushort f2bf(float f) {
    union { float f; unsigned u; } v; v.f = f;
    return (ushort)((v.u + 0x7fffu + ((v.u >> 16) & 1u)) >> 16);
}
__device__ __forceinline__ float bf2f(ushort u) {
    union { unsigned u; float f; } v; v.u = ((unsigned)u) << 16;
    return v.f;
}

// async global->LDS, 16B per lane, lands at ldsbase + lane*16
typedef const __attribute__((address_space(1))) unsigned int* gas_t;
typedef __attribute__((address_space(3))) unsigned int* las_t;
__device__ __forceinline__ void gl_lds16(const void* g, void* l) {
    __builtin_amdgcn_global_load_lds((gas_t)g, (las_t)l, 16, 0, 0);
}

// ---------------------------------------------------------------------------
// prep: xb = bf16(x) (2048 blocks); LDS-tiled coalesced transposes:
// wqkvT[n][k] = bf16(w_qkv[k][n]) (192 blocks); woT[n][k] = bf16(w_out[k][n]) (64)
// ---------------------------------------------------------------------------
__global__ __launch_bounds__(256) void prep_kernel(
    const float* __restrict__ x, const float* __restrict__ wqkv,
    const float* __restrict__ wo,
    ushort* __restrict__ xb, ushort* __restrict__ wqkvT, ushort* __restrict__ woT)
{
    __shared__ ushort tile[64][72];
    const int bx = blockIdx.x;
    const int t = threadIdx.x;
    if (bx < 2048) {                       // x: 4.19M elems, 8 per thread
        int gid = bx * 256 + t;
        const float4* xv = (const float4*)x;
        float4 v0 = xv[gid * 2], v1 = xv[gid * 2 + 1];
        uint4 pk;
        pk.x = (unsigned)f2bf(v0.x) | ((unsigned)f2bf(v0.y) << 16);
        pk.y = (unsigned)f2bf(v0.z) | ((unsigned)f2bf(v0.w) << 16);
        pk.z = (unsigned)f2bf(v1.x) | ((unsigned)f2bf(v1.y) << 16);
        pk.w = (unsigned)f2bf(v1.z) | ((unsigned)f2bf(v1.w) << 16);
        ((uint4*)xb)[gid] = pk;
        return;
    }
    int bi = bx - 2048;
    const float* src; ushort* dst; int C, tc, tr;
    if (bi < 192) { src = wqkv; dst = wqkvT; C = 1536; tc = bi % 24; tr = bi / 24; }
    else { bi -= 192; src = wo; dst = woT; C = 512; tc = bi & 7; tr = bi >> 3; }

    const int row = t >> 2, c16 = (t & 3) * 16;
    const float* sp = src + (size_t)(tr * 64 + row) * C + tc * 64 + c16;
    #pragma unroll
    for (int i = 0; i < 4; ++i) {
        float4 v = ((const float4*)sp)[i];
        tile[row][c16 + i * 4 + 0] = f2bf(v.x);
        tile[row][c16 + i * 4 + 1] = f2bf(v.y);
        tile[row][c16 + i * 4 + 2] = f2bf(v.z);
        tile[row][c16 + i * 4 + 3] = f2bf(v.w);
    }
    __syncthreads();
    ushort s[16];
    #pragma unroll
    for (int i = 0; i < 16; ++i) s[i] = tile[c16 + i][row];
    ushort* dp = dst + (size_t)(tc * 64 + row) * 512 + tr * 64 + c16;
    *(uint4*)dp       = *(uint4*)&s[0];
    *(uint4*)(dp + 8) = *(uint4*)&s[8];
}

// ---------------------------------------------------------------------------
// qkv_gemm: (8192,512)bf16 @ wqkvT(1536,512)bf16 -> q/k/v (B,H,N,DH) bf16
// mask-aware early-out for dead Q/K tiles; V blocks also write vT directly
// (fused vtrans).  [r6: verified, part of the 292 us best]
// ---------------------------------------------------------------------------
__global__ __launch_bounds__(256) void qkv_gemm(
    const ushort* __restrict__ A, const ushort* __restrict__ Bt,
    const int* __restrict__ mask,
    ushort* __restrict__ qb, ushort* __restrict__ kb, ushort* __restrict__ vb,
    ushort* __restrict__ vT)
{
    __shared__ ushort sA[128 * 64];
    __shared__ ushort sB[128 * 64];
    const int bn = blockIdx.x;       // 0..11
    const int bm = blockIdx.y;       // 0..63
    if (bn < 8 && mask[bm >> 4] != 0) return;   // dead Q/K tile (block-uniform)

    const int t = threadIdx.x, w_id = t >> 6, lane = t & 63;
    const int l15 = lane & 15, quad = lane >> 4;
    const int mo = (w_id & 1) * 64, no = (w_id >> 1) * 64;
    const int lr = lane >> 3, lc = (lane & 7) * 8;

    f32x4 acc[4][4] = {};

    for (int kt = 0; kt < 8; ++kt) {
        __syncthreads();
        #pragma unroll
        for (int i = 0; i < 4; ++i) {
            int j = w_id * 4 + i;
            gl_lds16(A  + (size_t)(bm * 128 + j * 8 + lr) * 512 + kt * 64 + lc, &sA[j * 512]);
            gl_lds16(Bt + (size_t)(bn * 128 + j * 8 + lr) * 512 + kt * 64 + lc, &sB[j * 512]);
        }
        __syncthreads();
        #pragma unroll
        for (int c = 0; c < 2; ++c) {
            short8 af[4], bf[4];
            #pragma unroll
            for (int mt = 0; mt < 4; ++mt)
                af[mt] = *(const short8*)&sA[(mo + mt * 16 + l15) * 64 + c * 32 + quad * 8];
            #pragma unroll
            for (int n2 = 0; n2 < 4; ++n2)
                bf[n2] = *(const short8*)&sB[(no + n2 * 16 + l15) * 64 + c * 32 + quad * 8];
            #pragma unroll
            for (int mt = 0; mt < 4; ++mt)
                #pragma unroll
                for (int n2 = 0; n2 < 4; ++n2)
                    acc[mt][n2] = __builtin_amdgcn_mfma_f32_16x16x32_bf16(af[mt], bf[n2], acc[mt][n2], 0, 0, 0);
        }
    }

    const int gn0 = bn * 128 + no;
    const int which = gn0 >> 9;
    const int h = (gn0 >> 6) & 7;
    ushort* dst = which == 0 ? qb : (which == 1 ? kb : vb);
    const float sc = which == 0 ? 0.125f : 1.0f;
    #pragma unroll
    for (int mt = 0; mt < 4; ++mt) {
        const int m0 = bm * 128 + mo + mt * 16 + quad * 4;
        #pragma unroll
        for (int n2 = 0; n2 < 4; ++n2) {
            int d = n2 * 16 + l15;
            ushort w0, w1, w2, w3;
            #pragma unroll
            for (int r = 0; r < 4; ++r) {
                int m = m0 + r, b = m >> 11, n = m & 2047;
                ushort bfv = f2bf(acc[mt][n2][r] * sc);
                dst[((size_t)(b * 8 + h) * 2048 + n) * 64 + d] = bfv;
                if (r == 0) w0 = bfv; else if (r == 1) w1 = bfv;
                else if (r == 2) w2 = bfv; else w3 = bfv;
            }
            if (which == 2) {                   // fused vtrans: vT[bh*64+d][n0..n0+3]
                int b = m0 >> 11, n0 = m0 & 2047;
                uint2 pk;
                pk.x = (unsigned)w0 | ((unsigned)w1 << 16);
                pk.y = (unsigned)w2 | ((unsigned)w3 << 16);
                *(uint2*)&vT[((size_t)(b * 8 + h) * 64 + d) * 2048 + n0] = pk;
            }
        }
    }
}

// ---------------------------------------------------------------------------
// Flash attention, fixed-max softmax.  v7 = v0 structure VERBATIM (proven
// 84 us; all schedule rewrites r2-r5 regressed) + ONE isolated change: the
// K/V LDS XOR swizzle (pre-swizzled global source since global_load_lds
// writes linearly; swizzled fragment reads).  Clean A/B on the 1.26e7
// bank-conflict counter: if attn drops, conflicts were critical-path; if
// neutral with conflicts ~0, attn is a confirmed local optimum.
// P scratch unchanged (stride 68).  K-split x2.  Unnormalized O + row sums.
// ---------------------------------------------------------------------------
__global__ __launch_bounds__(256) void attn_kernel(
    const ushort* __restrict__ qg, const ushort* __restrict__ kg,
    const ushort* __restrict__ vTg, const float* __restrict__ bias,
    const int* __restrict__ mask,
    ushort* __restrict__ po, float* __restrict__ pl)
{
    const int bid = blockIdx.x;
    const int qblk = bid & 31, s = (bid >> 5) & 1, h = (bid >> 6) & 7, b = bid >> 9;
    if (mask[b] != 0) return;                   // handled downstream (O = v)

    const int t = threadIdx.x, w_id = t >> 6, lane = t & 63;
    const int l15 = lane & 15, quad = lane >> 4;
    const int lr = lane >> 3;
    const int lcs = ((lane & 7) ^ lr) * 8;      // pre-swizzled source chunk
    const int rsw = l15 & 7;                    // read-side row swizzle key
    const int bh = b * 8 + h;
    const int kbase = s * 1024;

    __shared__ ushort lds_k[64 * 64];
    __shared__ ushort lds_vt[64 * 64];
    __shared__ ushort lds_sp[4 * 16 * 68];      // per-wave P, stride 68 (bank-safe)

    const ushort* kptr = kg  + (size_t)bh * 2048 * 64;
    const ushort* vtp  = vTg + (size_t)bh * 64 * 2048;

    const ushort* qrp = qg + (size_t)bh * 2048 * 64 + (size_t)(qblk * 64 + w_id * 16 + l15) * 64;
    short8 qf0 = *(const short8*)(qrp + quad * 8);
    short8 qf1 = *(const short8*)(qrp + 32 + quad * 8);

    const int qrow0 = qblk * 64 + w_id * 16 + quad * 4;
    const float* bp = bias + ((size_t)h * 2048 + qrow0) * 2048 + kbase;

    float breg[16];
    #pragma unroll
    for (int tt = 0; tt < 4; ++tt)
        #pragma unroll
        for (int r = 0; r < 4; ++r)
            breg[tt * 4 + r] = bp[(size_t)r * 2048 + tt * 16 + l15];

    f32x4 o[4] = {};
    float lsum[4] = {0.f, 0.f, 0.f, 0.f};

    for (int it = 0; it < 16; ++it) {
        __syncthreads();
        #pragma unroll
        for (int i = 0; i < 2; ++i) {
            int j = w_id * 2 + i;
            gl_lds16(kptr + (size_t)(kbase + it * 64 + j * 8 + lr) * 64 + lcs, &lds_k[j * 512]);
            gl_lds16(vtp + (size_t)(j * 8 + lr) * 2048 + kbase + it * 64 + lcs, &lds_vt[j * 512]);
        }
        __syncthreads();

        // S = Q K^T + bias  (swizzled reads: conflict-free)
        f32x4 sv[4] = {};
        #pragma unroll
        for (int tt = 0; tt < 4; ++tt) {
            const ushort* kr = &lds_k[(tt * 16 + l15) * 64];
            short8 kf0 = *(const short8*)&kr[(quad ^ rsw) * 8];
            short8 kf1 = *(const short8*)&kr[((4 + quad) ^ rsw) * 8];
            sv[tt] = __builtin_amdgcn_mfma_f32_16x16x32_bf16(qf0, kf0, sv[tt], 0, 0, 0);
            sv[tt] = __builtin_amdgcn_mfma_f32_16x16x32_bf16(qf1, kf1, sv[tt], 0, 0, 0);
        }
        #pragma unroll
        for (int tt = 0; tt < 4; ++tt)
            #pragma unroll
            for (int r = 0; r < 4; ++r)
                sv[tt][r] += breg[tt * 4 + r];

        if (it < 15) {                           // prefetch next bias chunk
            #pragma unroll
            for (int tt = 0; tt < 4; ++tt)
                #pragma unroll
                for (int r = 0; r < 4; ++r)
                    breg[tt * 4 + r] = bp[(size_t)r * 2048 + (it + 1) * 64 + tt * 16 + l15];
        }

        // P = exp(S), per-lane partial row sums (no cross-lane work here)
        const int prow0 = (w_id * 16 + quad * 4) * 68;
        #pragma unroll
        for (int r = 0; r < 4; ++r) {
            float e0 = __expf(sv[0][r]), e1 = __expf(sv[1][r]);
            float e2 = __expf(sv[2][r]), e3 = __expf(sv[3][r]);
            lsum[r] += (e0 + e1) + (e2 + e3);
            const int pr = prow0 + r * 68;
            lds_sp[pr + l15]      = f2bf(e0);
            lds_sp[pr + 16 + l15] = f2bf(e1);
            lds_sp[pr + 32 + l15] = f2bf(e2);
            lds_sp[pr + 48 + l15] = f2bf(e3);
        }

        // P region is wave-private: wave-level LDS fence suffices
        asm volatile("s_waitcnt lgkmcnt(0)" ::: "memory");

        short8 pf0 = *(const short8*)&lds_sp[(w_id * 16 + l15) * 68 + quad * 8];
        short8 pf1 = *(const short8*)&lds_sp[(w_id * 16 + l15) * 68 + 32 + quad * 8];
        #pragma unroll
        for (int nt = 0; nt < 4; ++nt) {
            const ushort* vr = &lds_vt[(nt * 16 + l15) * 64];
            short8 vf0 = *(const short8*)&vr[(quad ^ rsw) * 8];
            short8 vf1 = *(const short8*)&vr[((4 + quad) ^ rsw) * 8];
            o[nt] = __builtin_amdgcn_mfma_f32_16x16x32_bf16(pf0, vf0, o[nt], 0, 0, 0);
            o[nt] = __builtin_amdgcn_mfma_f32_16x16x32_bf16(pf1, vf1, o[nt], 0, 0, 0);
        }
    }

    // reduce row sums across the 16 lanes holding each row (once, at the end)
    #pragma unroll
    for (int r = 0; r < 4; ++r) {
        #pragma unroll
        for (int off = 1; off < 16; off <<= 1)
            lsum[r] += __shfl_xor(lsum[r], off, 64);
    }

    #pragma unroll
    for (int r = 0; r < 4; ++r) {
        const int qrow = qrow0 + r;
        const size_t base = ((size_t)(s * 32 + bh) * 2048 + qrow) * 64;
        #pragma unroll
        for (int nt = 0; nt < 4; ++nt)
            po[base + nt * 16 + l15] = f2bf(o[nt][r]);      // unnormalized
        if (l15 == 0)
            pl[(size_t)(s * 32 + bh) * 2048 + qrow] = lsum[r];
    }
}

// ---------------------------------------------------------------------------
// out_gemm v7: combine FUSED into A-staging.  The kt-th K-tile of A is
// exactly head kt's combined attention output for rows bm*128..+127
// (kt == head index since K = 512 = 8 heads x 64 dims).  sA is reg-staged:
// (po1+po2)/(l1+l2) for unmasked batches, vb for masked (block-uniform
// branch: batch = bm>>4).  combine_kernel + ob buffer deleted.
// Single-buffer 32 KB LDS (5 blocks/CU), 2-barrier loop; sB async via
// gl_lds16 with swizzle; sA ds_write with matching write-side swizzle.
// ---------------------------------------------------------------------------
__global__ __launch_bounds__(256) void out_gemm(
    const ushort* __restrict__ po, const float* __restrict__ pl,
    const ushort* __restrict__ vb, const int* __restrict__ mask,
    const ushort* __restrict__ Bt, float* __restrict__ out)
{
    __shared__ ushort sA[128 * 64];
    __shared__ ushort sB[128 * 64];
    const int bn = blockIdx.x;       // 0..3
    const int bm = blockIdx.y;       // 0..63
    const int t = threadIdx.x, w_id = t >> 6, lane = t & 63;
    const int l15 = lane & 15, quad = lane >> 4;
    const int mo = (w_id & 1) * 64, no = (w_id >> 1) * 64;
    const int lr = lane >> 3, lc = (lane & 7) * 8;
    const int lcs = ((lane & 7) ^ lr) * 8;      // pre-swizzled source chunk (sB)
    const int rsw = l15 & 7;                    // read-side row swizzle key
    const int b = bm >> 4;                      // batch (block-uniform)
    const int msk = mask[b];

    f32x4 acc[4][4] = {};

    for (int kt = 0; kt < 8; ++kt) {            // kt == head h
        __syncthreads();
        // sB: weights, async staged (pre-swizzled source)
        #pragma unroll
        for (int i = 0; i < 4; ++i) {
            int j = w_id * 4 + i;
            gl_lds16(Bt + (size_t)(bn * 128 + j * 8 + lr) * 512 + kt * 64 + lcs, &sB[j * 512]);
        }
        // sA: fused combine, reg-staged with write-side swizzle
        #pragma unroll
        for (int i = 0; i < 4; ++i) {
            int j = w_id * 4 + i;
            int row = bm * 128 + j * 8 + lr;        // 0..8191
            int n = row & 2047;
            ushort v8[8];
            if (msk != 0) {
                *(uint4*)v8 = *(const uint4*)&vb[((size_t)(b * 8 + kt) * 2048 + n) * 64 + lc];
            } else {
                const size_t i1 = (size_t)(b * 8 + kt) * 2048 + n;
                const size_t i2 = (size_t)(32 + b * 8 + kt) * 2048 + n;
                uint4 ua = *(const uint4*)&po[i1 * 64 + lc];
                uint4 ub = *(const uint4*)&po[i2 * 64 + lc];
                float inv = 1.f / (pl[i1] + pl[i2]);
                const ushort* pa = (const ushort*)&ua;
                const ushort* pb = (const ushort*)&ub;
                #pragma unroll
                for (int e = 0; e < 8; ++e)
                    v8[e] = f2bf((bf2f(pa[e]) + bf2f(pb[e])) * inv);
            }
            // LDS[row][c] = global[row][c ^ (row&7)]  (write-side swizzle)
            *(uint4*)&sA[j * 512 + lr * 64 + (((lane & 7) ^ lr)) * 8] = *(uint4*)v8;
        }
        __syncthreads();                        // drains ds_write + gl_lds16

        #pragma unroll
        for (int c = 0; c < 2; ++c) {
            short8 af[4], bf[4];
            #pragma unroll
            for (int mt = 0; mt < 4; ++mt)
                af[mt] = *(const short8*)&sA[(mo + mt * 16 + l15) * 64 + (((c * 4 + quad) ^ rsw)) * 8];
            #pragma unroll
            for (int n2 = 0; n2 < 4; ++n2)
                bf[n2] = *(const short8*)&sB[(no + n2 * 16 + l15) * 64 + (((c * 4 + quad) ^ rsw)) * 8];
            #pragma unroll
            for (int mt = 0; mt < 4; ++mt)
                #pragma unroll
                for (int n2 = 0; n2 < 4; ++n2)
                    acc[mt][n2] = __builtin_amdgcn_mfma_f32_16x16x32_bf16(af[mt], bf[n2], acc[mt][n2], 0, 0, 0);
        }
    }
    #pragma unroll
    for (int mt = 0; mt < 4; ++mt) {
        const int m0 = bm * 128 + mo + mt * 16 + quad * 4;
        #pragma unroll
        for (int n2 = 0; n2 < 4; ++n2) {
            int col = bn * 128 + no + n2 * 16 + l15;
            #pragma unroll
            for (int r = 0; r < 4; ++r)
                out[(size_t)(m0 + r) * 512 + col] = acc[mt][n2][r];
        }
    }
}

// ---------------------------------------------------------------------------
extern "C" void kernel_launch(void* const* d_in, const int* in_sizes, int n_in,
                              void* d_out, int out_size, void* d_ws, size_t ws_size,
                              hipStream_t stream)
{
    const float* x        = (const float*)d_in[0];
    const float* pos_bias = (const float*)d_in[1];
    const int*   mask     = (const int*)d_in[2];
    const float* w_qkv    = (const float*)d_in[3];
    const float* w_out    = (const float*)d_in[4];
    float* out = (float*)d_out;

    char* ws = (char*)d_ws;
    ushort* qb    = (ushort*)(ws + 0);            //  8,388,608
    ushort* kb    = (ushort*)(ws + 8388608);      //  8,388,608
    ushort* vb    = (ushort*)(ws + 16777216);     //  8,388,608
    ushort* vT    = (ushort*)(ws + 25165824);     //  8,388,608
    ushort* xb    = (ushort*)(ws + 33554432);     //  8,388,608
    ushort* po    = (ushort*)(ws + 41943040);     // 16,777,216
    float*  pl    = (float* )(ws + 58720256);     //    524,288
    ushort* woT   = (ushort*)(ws + 59244544);     //    524,288
    ushort* wqkvT = (ushort*)(ws + 59768832);     //  1,572,864

    prep_kernel<<<2304, 256, 0, stream>>>(x, w_qkv, w_out, xb, wqkvT, woT);
    qkv_gemm<<<dim3(12, 64), 256, 0, stream>>>(xb, wqkvT, mask, qb, kb, vb, vT);
    attn_kernel<<<2048, 256, 0, stream>>>(qb, kb, vT, pos_bias, mask, po, pl);
    out_gemm<<<dim3(4, 64), 256, 0, stream>>>(po, pl, vb, mask, woT, out);
}

// Round 8
// 281.590 us; speedup vs baseline: 1.0402x; 1.0402x over previous
//
#include <hip/hip_runtime.h>
#include <hip/hip_bf16.h>
#include <float.h>

#define B_   4
#define N_   2048
#define DIM_ 512
#define H_   8
#define DH_  64

typedef unsigned short ushort;
typedef __attribute__((ext_vector_type(8))) short short8;
typedef __attribute__((ext_vector_type(4))) float f32x4;

__device__ __forceinline__ ushort f2bf(float f) {
    union { float f; unsigned u; } v; v.f = f;
    return (ushort)((v.u + 0x7fffu + ((v.u >> 16) & 1u)) >> 16);
}
__device__ __forceinline__ float bf2f(ushort u) {
    union { unsigned u; float f; } v; v.u = ((unsigned)u) << 16;
    return v.f;
}

// async global->LDS, 16B per lane, lands at ldsbase + lane*16
typedef const __attribute__((address_space(1))) unsigned int* gas_t;
typedef __attribute__((address_space(3))) unsigned int* las_t;
__device__ __forceinline__ void gl_lds16(const void* g, void* l) {
    __builtin_amdgcn_global_load_lds((gas_t)g, (las_t)l, 16, 0, 0);
}

// ---------------------------------------------------------------------------
// prep: xb = bf16(x) (2048 blocks); LDS-tiled coalesced transposes:
// wqkvT[n][k] = bf16(w_qkv[k][n]) (192 blocks); woT[n][k] = bf16(w_out[k][n]) (64)
// ---------------------------------------------------------------------------
__global__ __launch_bounds__(256) void prep_kernel(
    const float* __restrict__ x, const float* __restrict__ wqkv,
    const float* __restrict__ wo,
    ushort* __restrict__ xb, ushort* __restrict__ wqkvT, ushort* __restrict__ woT)
{
    __shared__ ushort tile[64][72];
    const int bx = blockIdx.x;
    const int t = threadIdx.x;
    if (bx < 2048) {                       // x: 4.19M elems, 8 per thread
        int gid = bx * 256 + t;
        const float4* xv = (const float4*)x;
        float4 v0 = xv[gid * 2], v1 = xv[gid * 2 + 1];
        uint4 pk;
        pk.x = (unsigned)f2bf(v0.x) | ((unsigned)f2bf(v0.y) << 16);
        pk.y = (unsigned)f2bf(v0.z) | ((unsigned)f2bf(v0.w) << 16);
        pk.z = (unsigned)f2bf(v1.x) | ((unsigned)f2bf(v1.y) << 16);
        pk.w = (unsigned)f2bf(v1.z) | ((unsigned)f2bf(v1.w) << 16);
        ((uint4*)xb)[gid] = pk;
        return;
    }
    int bi = bx - 2048;
    const float* src; ushort* dst; int C, tc, tr;
    if (bi < 192) { src = wqkv; dst = wqkvT; C = 1536; tc = bi % 24; tr = bi / 24; }
    else { bi -= 192; src = wo; dst = woT; C = 512; tc = bi & 7; tr = bi >> 3; }

    const int row = t >> 2, c16 = (t & 3) * 16;
    const float* sp = src + (size_t)(tr * 64 + row) * C + tc * 64 + c16;
    #pragma unroll
    for (int i = 0; i < 4; ++i) {
        float4 v = ((const float4*)sp)[i];
        tile[row][c16 + i * 4 + 0] = f2bf(v.x);
        tile[row][c16 + i * 4 + 1] = f2bf(v.y);
        tile[row][c16 + i * 4 + 2] = f2bf(v.z);
        tile[row][c16 + i * 4 + 3] = f2bf(v.w);
    }
    __syncthreads();
    ushort s[16];
    #pragma unroll
    for (int i = 0; i < 16; ++i) s[i] = tile[c16 + i][row];
    ushort* dp = dst + (size_t)(tc * 64 + row) * 512 + tr * 64 + c16;
    *(uint4*)dp       = *(uint4*)&s[0];
    *(uint4*)(dp + 8) = *(uint4*)&s[8];
}

// ---------------------------------------------------------------------------
// qkv_gemm: (8192,512)bf16 @ wqkvT(1536,512)bf16 -> q/k/v (B,H,N,DH) bf16
// mask-aware early-out for dead Q/K tiles; V blocks also write vT directly
// (fused vtrans).  [r6: verified part of the best]
// v8: + XOR swizzle on sA/sB (same geometry as attn's 16-way conflict,
// same transform proven -4.7us on attn in r7): lc->lcs staging source,
// (c*4+quad)^rsw fragment reads.
// ---------------------------------------------------------------------------
__global__ __launch_bounds__(256) void qkv_gemm(
    const ushort* __restrict__ A, const ushort* __restrict__ Bt,
    const int* __restrict__ mask,
    ushort* __restrict__ qb, ushort* __restrict__ kb, ushort* __restrict__ vb,
    ushort* __restrict__ vT)
{
    __shared__ ushort sA[128 * 64];
    __shared__ ushort sB[128 * 64];
    const int bn = blockIdx.x;       // 0..11
    const int bm = blockIdx.y;       // 0..63
    if (bn < 8 && mask[bm >> 4] != 0) return;   // dead Q/K tile (block-uniform)

    const int t = threadIdx.x, w_id = t >> 6, lane = t & 63;
    const int l15 = lane & 15, quad = lane >> 4;
    const int mo = (w_id & 1) * 64, no = (w_id >> 1) * 64;
    const int lr = lane >> 3;
    const int lcs = ((lane & 7) ^ lr) * 8;      // pre-swizzled source chunk
    const int rsw = l15 & 7;                    // read-side row swizzle key

    f32x4 acc[4][4] = {};

    for (int kt = 0; kt < 8; ++kt) {
        __syncthreads();
        #pragma unroll
        for (int i = 0; i < 4; ++i) {
            int j = w_id * 4 + i;
            gl_lds16(A  + (size_t)(bm * 128 + j * 8 + lr) * 512 + kt * 64 + lcs, &sA[j * 512]);
            gl_lds16(Bt + (size_t)(bn * 128 + j * 8 + lr) * 512 + kt * 64 + lcs, &sB[j * 512]);
        }
        __syncthreads();
        #pragma unroll
        for (int c = 0; c < 2; ++c) {
            short8 af[4], bf[4];
            #pragma unroll
            for (int mt = 0; mt < 4; ++mt)
                af[mt] = *(const short8*)&sA[(mo + mt * 16 + l15) * 64 + (((c * 4 + quad) ^ rsw)) * 8];
            #pragma unroll
            for (int n2 = 0; n2 < 4; ++n2)
                bf[n2] = *(const short8*)&sB[(no + n2 * 16 + l15) * 64 + (((c * 4 + quad) ^ rsw)) * 8];
            #pragma unroll
            for (int mt = 0; mt < 4; ++mt)
                #pragma unroll
                for (int n2 = 0; n2 < 4; ++n2)
                    acc[mt][n2] = __builtin_amdgcn_mfma_f32_16x16x32_bf16(af[mt], bf[n2], acc[mt][n2], 0, 0, 0);
        }
    }

    const int gn0 = bn * 128 + no;
    const int which = gn0 >> 9;
    const int h = (gn0 >> 6) & 7;
    ushort* dst = which == 0 ? qb : (which == 1 ? kb : vb);
    const float sc = which == 0 ? 0.125f : 1.0f;
    #pragma unroll
    for (int mt = 0; mt < 4; ++mt) {
        const int m0 = bm * 128 + mo + mt * 16 + quad * 4;
        #pragma unroll
        for (int n2 = 0; n2 < 4; ++n2) {
            int d = n2 * 16 + l15;
            ushort w0, w1, w2, w3;
            #pragma unroll
            for (int r = 0; r < 4; ++r) {
                int m = m0 + r, b = m >> 11, n = m & 2047;
                ushort bfv = f2bf(acc[mt][n2][r] * sc);
                dst[((size_t)(b * 8 + h) * 2048 + n) * 64 + d] = bfv;
                if (r == 0) w0 = bfv; else if (r == 1) w1 = bfv;
                else if (r == 2) w2 = bfv; else w3 = bfv;
            }
            if (which == 2) {                   // fused vtrans: vT[bh*64+d][n0..n0+3]
                int b = m0 >> 11, n0 = m0 & 2047;
                uint2 pk;
                pk.x = (unsigned)w0 | ((unsigned)w1 << 16);
                pk.y = (unsigned)w2 | ((unsigned)w3 << 16);
                *(uint2*)&vT[((size_t)(b * 8 + h) * 64 + d) * 2048 + n0] = pk;
            }
        }
    }
}

// ---------------------------------------------------------------------------
// Flash attention v7 (UNCHANGED — proven 80 us in r7): v0 structure + K/V
// XOR swizzle (conflicts 1.26e7 -> 0, -4.7 us).  Schedule rewrites all
// regressed (r2-r5): do not touch.  K-split x2.  Unnormalized O + row sums.
// ---------------------------------------------------------------------------
__global__ __launch_bounds__(256) void attn_kernel(
    const ushort* __restrict__ qg, const ushort* __restrict__ kg,
    const ushort* __restrict__ vTg, const float* __restrict__ bias,
    const int* __restrict__ mask,
    ushort* __restrict__ po, float* __restrict__ pl)
{
    const int bid = blockIdx.x;
    const int qblk = bid & 31, s = (bid >> 5) & 1, h = (bid >> 6) & 7, b = bid >> 9;
    if (mask[b] != 0) return;                   // handled in combine (O = v)

    const int t = threadIdx.x, w_id = t >> 6, lane = t & 63;
    const int l15 = lane & 15, quad = lane >> 4;
    const int lr = lane >> 3;
    const int lcs = ((lane & 7) ^ lr) * 8;      // pre-swizzled source chunk
    const int rsw = l15 & 7;                    // read-side row swizzle key
    const int bh = b * 8 + h;
    const int kbase = s * 1024;

    __shared__ ushort lds_k[64 * 64];
    __shared__ ushort lds_vt[64 * 64];
    __shared__ ushort lds_sp[4 * 16 * 68];      // per-wave P, stride 68 (bank-safe)

    const ushort* kptr = kg  + (size_t)bh * 2048 * 64;
    const ushort* vtp  = vTg + (size_t)bh * 64 * 2048;

    const ushort* qrp = qg + (size_t)bh * 2048 * 64 + (size_t)(qblk * 64 + w_id * 16 + l15) * 64;
    short8 qf0 = *(const short8*)(qrp + quad * 8);
    short8 qf1 = *(const short8*)(qrp + 32 + quad * 8);

    const int qrow0 = qblk * 64 + w_id * 16 + quad * 4;
    const float* bp = bias + ((size_t)h * 2048 + qrow0) * 2048 + kbase;

    float breg[16];
    #pragma unroll
    for (int tt = 0; tt < 4; ++tt)
        #pragma unroll
        for (int r = 0; r < 4; ++r)
            breg[tt * 4 + r] = bp[(size_t)r * 2048 + tt * 16 + l15];

    f32x4 o[4] = {};
    float lsum[4] = {0.f, 0.f, 0.f, 0.f};

    for (int it = 0; it < 16; ++it) {
        __syncthreads();
        #pragma unroll
        for (int i = 0; i < 2; ++i) {
            int j = w_id * 2 + i;
            gl_lds16(kptr + (size_t)(kbase + it * 64 + j * 8 + lr) * 64 + lcs, &lds_k[j * 512]);
            gl_lds16(vtp + (size_t)(j * 8 + lr) * 2048 + kbase + it * 64 + lcs, &lds_vt[j * 512]);
        }
        __syncthreads();

        // S = Q K^T + bias  (swizzled reads: conflict-free)
        f32x4 sv[4] = {};
        #pragma unroll
        for (int tt = 0; tt < 4; ++tt) {
            const ushort* kr = &lds_k[(tt * 16 + l15) * 64];
            short8 kf0 = *(const short8*)&kr[(quad ^ rsw) * 8];
            short8 kf1 = *(const short8*)&kr[((4 + quad) ^ rsw) * 8];
            sv[tt] = __builtin_amdgcn_mfma_f32_16x16x32_bf16(qf0, kf0, sv[tt], 0, 0, 0);
            sv[tt] = __builtin_amdgcn_mfma_f32_16x16x32_bf16(qf1, kf1, sv[tt], 0, 0, 0);
        }
        #pragma unroll
        for (int tt = 0; tt < 4; ++tt)
            #pragma unroll
            for (int r = 0; r < 4; ++r)
                sv[tt][r] += breg[tt * 4 + r];

        if (it < 15) {                           // prefetch next bias chunk
            #pragma unroll
            for (int tt = 0; tt < 4; ++tt)
                #pragma unroll
                for (int r = 0; r < 4; ++r)
                    breg[tt * 4 + r] = bp[(size_t)r * 2048 + (it + 1) * 64 + tt * 16 + l15];
        }

        // P = exp(S), per-lane partial row sums (no cross-lane work here)
        const int prow0 = (w_id * 16 + quad * 4) * 68;
        #pragma unroll
        for (int r = 0; r < 4; ++r) {
            float e0 = __expf(sv[0][r]), e1 = __expf(sv[1][r]);
            float e2 = __expf(sv[2][r]), e3 = __expf(sv[3][r]);
            lsum[r] += (e0 + e1) + (e2 + e3);
            const int pr = prow0 + r * 68;
            lds_sp[pr + l15]      = f2bf(e0);
            lds_sp[pr + 16 + l15] = f2bf(e1);
            lds_sp[pr + 32 + l15] = f2bf(e2);
            lds_sp[pr + 48 + l15] = f2bf(e3);
        }

        // P region is wave-private: wave-level LDS fence suffices
        asm volatile("s_waitcnt lgkmcnt(0)" ::: "memory");

        short8 pf0 = *(const short8*)&lds_sp[(w_id * 16 + l15) * 68 + quad * 8];
        short8 pf1 = *(const short8*)&lds_sp[(w_id * 16 + l15) * 68 + 32 + quad * 8];
        #pragma unroll
        for (int nt = 0; nt < 4; ++nt) {
            const ushort* vr = &lds_vt[(nt * 16 + l15) * 64];
            short8 vf0 = *(const short8*)&vr[(quad ^ rsw) * 8];
            short8 vf1 = *(const short8*)&vr[((4 + quad) ^ rsw) * 8];
            o[nt] = __builtin_amdgcn_mfma_f32_16x16x32_bf16(pf0, vf0, o[nt], 0, 0, 0);
            o[nt] = __builtin_amdgcn_mfma_f32_16x16x32_bf16(pf1, vf1, o[nt], 0, 0, 0);
        }
    }

    // reduce row sums across the 16 lanes holding each row (once, at the end)
    #pragma unroll
    for (int r = 0; r < 4; ++r) {
        #pragma unroll
        for (int off = 1; off < 16; off <<= 1)
            lsum[r] += __shfl_xor(lsum[r], off, 64);
    }

    #pragma unroll
    for (int r = 0; r < 4; ++r) {
        const int qrow = qrow0 + r;
        const size_t base = ((size_t)(s * 32 + bh) * 2048 + qrow) * 64;
        #pragma unroll
        for (int nt = 0; nt < 4; ++nt)
            po[base + nt * 16 + l15] = f2bf(o[nt][r]);      // unnormalized
        if (l15 == 0)
            pl[(size_t)(s * 32 + bh) * 2048 + qrow] = lsum[r];
    }
}

// ---------------------------------------------------------------------------
// combine: ob = (O1 + O2) / (l1 + l2); masked batches: ob = v
// (restored from r6 — the fused-into-out_gemm variant cost ~+5 us in r7)
// ---------------------------------------------------------------------------
__global__ __launch_bounds__(256) void combine_kernel(
    const ushort* __restrict__ po, const float* __restrict__ pl,
    const ushort* __restrict__ vb, const int* __restrict__ mask,
    ushort* __restrict__ ob)
{
    const int gid = blockIdx.x * 256 + threadIdx.x;    // 524288
    const int dd = (gid & 7) * 8;
    const int h = (gid >> 3) & 7, n = (gid >> 6) & 2047, b = gid >> 17;
    const int bh = b * 8 + h;
    ushort* op = ob + ((size_t)b * 2048 + n) * 512 + h * 64 + dd;
    if (mask[b] != 0) {
        *(uint4*)op = *(const uint4*)(vb + ((size_t)bh * 2048 + n) * 64 + dd);
        return;
    }
    const size_t i1 = (size_t)bh * 2048 + n;
    const size_t i2 = (size_t)(32 + bh) * 2048 + n;
    float inv = 1.f / (pl[i1] + pl[i2]);
    uint4 ua = *(const uint4*)(po + i1 * 64 + dd);
    uint4 ub = *(const uint4*)(po + i2 * 64 + dd);
    const ushort* pa = (const ushort*)&ua;
    const ushort* pb = (const ushort*)&ub;
    ushort res[8];
    #pragma unroll
    for (int j = 0; j < 8; ++j)
        res[j] = f2bf((bf2f(pa[j]) + bf2f(pb[j])) * inv);
    *(uint4*)op = *(uint4*)res;
}

// ---------------------------------------------------------------------------
// out_gemm: ob(8192,512)bf16 @ woT(512,512)bf16 -> out fp32
// (r6 version restored: dbuf + stage-before-compute + swizzle; 1 block/CU
// grid so intra-block overlap is the only latency hiding.)
// ---------------------------------------------------------------------------
__global__ __launch_bounds__(256) void out_gemm(
    const ushort* __restrict__ A, const ushort* __restrict__ Bt,
    float* __restrict__ out)
{
    __shared__ ushort sA[2][128 * 64];
    __shared__ ushort sB[2][128 * 64];
    const int bn = blockIdx.x;       // 0..3
    const int bm = blockIdx.y;       // 0..63
    const int t = threadIdx.x, w_id = t >> 6, lane = t & 63;
    const int l15 = lane & 15, quad = lane >> 4;
    const int mo = (w_id & 1) * 64, no = (w_id >> 1) * 64;
    const int lr = lane >> 3;
    const int lcs = ((lane & 7) ^ lr) * 8;      // pre-swizzled source chunk
    const int rsw = l15 & 7;

    f32x4 acc[4][4] = {};

    // prologue stage kt=0 into buf 0
    #pragma unroll
    for (int i = 0; i < 4; ++i) {
        int j = w_id * 4 + i;
        gl_lds16(A  + (size_t)(bm * 128 + j * 8 + lr) * 512 + lcs, &sA[0][j * 512]);
        gl_lds16(Bt + (size_t)(bn * 128 + j * 8 + lr) * 512 + lcs, &sB[0][j * 512]);
    }
    asm volatile("s_waitcnt vmcnt(0)" ::: "memory");
    __syncthreads();

    for (int kt = 0; kt < 8; ++kt) {
        const int cur = kt & 1;
        if (kt + 1 < 8) {
            #pragma unroll
            for (int i = 0; i < 4; ++i) {
                int j = w_id * 4 + i;
                gl_lds16(A  + (size_t)(bm * 128 + j * 8 + lr) * 512 + (kt + 1) * 64 + lcs,
                         &sA[cur ^ 1][j * 512]);
                gl_lds16(Bt + (size_t)(bn * 128 + j * 8 + lr) * 512 + (kt + 1) * 64 + lcs,
                         &sB[cur ^ 1][j * 512]);
            }
        }
        #pragma unroll
        for (int c = 0; c < 2; ++c) {
            short8 af[4], bf[4];
            #pragma unroll
            for (int mt = 0; mt < 4; ++mt)
                af[mt] = *(const short8*)&sA[cur][(mo + mt * 16 + l15) * 64 + (((c * 4 + quad) ^ rsw)) * 8];
            #pragma unroll
            for (int n2 = 0; n2 < 4; ++n2)
                bf[n2] = *(const short8*)&sB[cur][(no + n2 * 16 + l15) * 64 + (((c * 4 + quad) ^ rsw)) * 8];
            #pragma unroll
            for (int mt = 0; mt < 4; ++mt)
                #pragma unroll
                for (int n2 = 0; n2 < 4; ++n2)
                    acc[mt][n2] = __builtin_amdgcn_mfma_f32_16x16x32_bf16(af[mt], bf[n2], acc[mt][n2], 0, 0, 0);
        }
        asm volatile("s_waitcnt vmcnt(0)" ::: "memory");
        __syncthreads();
    }
    #pragma unroll
    for (int mt = 0; mt < 4; ++mt) {
        const int m0 = bm * 128 + mo + mt * 16 + quad * 4;
        #pragma unroll
        for (int n2 = 0; n2 < 4; ++n2) {
            int col = bn * 128 + no + n2 * 16 + l15;
            #pragma unroll
            for (int r = 0; r < 4; ++r)
                out[(size_t)(m0 + r) * 512 + col] = acc[mt][n2][r];
        }
    }
}

// ---------------------------------------------------------------------------
extern "C" void kernel_launch(void* const* d_in, const int* in_sizes, int n_in,
                              void* d_out, int out_size, void* d_ws, size_t ws_size,
                              hipStream_t stream)
{
    const float* x        = (const float*)d_in[0];
    const float* pos_bias = (const float*)d_in[1];
    const int*   mask     = (const int*)d_in[2];
    const float* w_qkv    = (const float*)d_in[3];
    const float* w_out    = (const float*)d_in[4];
    float* out = (float*)d_out;

    char* ws = (char*)d_ws;
    ushort* qb    = (ushort*)(ws + 0);            //  8,388,608
    ushort* kb    = (ushort*)(ws + 8388608);      //  8,388,608
    ushort* vb    = (ushort*)(ws + 16777216);     //  8,388,608
    ushort* vT    = (ushort*)(ws + 25165824);     //  8,388,608
    ushort* xb    = (ushort*)(ws + 33554432);     //  8,388,608 (reused as ob)
    ushort* ob    = (ushort*)(ws + 33554432);
    ushort* po    = (ushort*)(ws + 41943040);     // 16,777,216
    float*  pl    = (float* )(ws + 58720256);     //    524,288
    ushort* woT   = (ushort*)(ws + 59244544);     //    524,288
    ushort* wqkvT = (ushort*)(ws + 59768832);     //  1,572,864

    prep_kernel<<<2304, 256, 0, stream>>>(x, w_qkv, w_out, xb, wqkvT, woT);
    qkv_gemm<<<dim3(12, 64), 256, 0, stream>>>(xb, wqkvT, mask, qb, kb, vb, vT);
    attn_kernel<<<2048, 256, 0, stream>>>(qb, kb, vT, pos_bias, mask, po, pl);
    combine_kernel<<<2048, 256, 0, stream>>>(po, pl, vb, mask, ob);
    out_gemm<<<dim3(4, 64), 256, 0, stream>>>(ob, woT, out);
}